// Round 4
// baseline (194.625 us; speedup 1.0000x reference)
//
#include <hip/hip_runtime.h>
#include <hip/hip_bf16.h>
#include <stdint.h>

#define BN 8192
#define DK 1024
#define NT 16           // K-steps of 64
#define NTILES 528      // 32*33/2 upper-triangle 256x256 tiles

typedef __attribute__((ext_vector_type(8))) short bf16x8;   // 8 bf16 (4 VGPRs)
typedef __attribute__((ext_vector_type(4))) float f32x4;

#define MFMA16(a, b, c) __builtin_amdgcn_mfma_f32_16x16x32_bf16((a), (b), (c), 0, 0, 0)
#define BAR() do { asm volatile("" ::: "memory"); __builtin_amdgcn_s_barrier(); asm volatile("" ::: "memory"); } while (0)

__device__ __forceinline__ unsigned short f2bf(float f) {
  unsigned int u = __float_as_uint(f);
  return (unsigned short)((u + 0x7fffu + ((u >> 16) & 1u)) >> 16);
}

// ---------------- prep: bf16 copy of x + fp32 row norms ----------------
__global__ __launch_bounds__(256) void snn_prep(const float* __restrict__ x,
                                                unsigned short* __restrict__ xb,
                                                float* __restrict__ xn) {
  const int row = blockIdx.x * 4 + (threadIdx.x >> 6);
  const int lane = threadIdx.x & 63;
  const float4* src = (const float4*)(x + (size_t)row * DK);
  ushort4* dst = (ushort4*)(xb + (size_t)row * DK);
  float s = 0.f;
#pragma unroll
  for (int i = 0; i < 4; ++i) {
    float4 v = src[lane + i * 64];
    s = fmaf(v.x, v.x, s); s = fmaf(v.y, v.y, s);
    s = fmaf(v.z, v.z, s); s = fmaf(v.w, v.w, s);
    ushort4 o;
    o.x = f2bf(v.x); o.y = f2bf(v.y); o.z = f2bf(v.z); o.w = f2bf(v.w);
    dst[lane + i * 64] = o;
  }
#pragma unroll
  for (int m = 32; m >= 1; m >>= 1) s += __shfl_xor(s, m);
  if (lane == 0) xn[row] = s;
}

// ---------------- main: 256^2 triangle tiles, 4-phase pipelined K-loop ----------------
// Phase skeleton (m201 template): {ds_reads; stage-issue; BAR; MFMA x16; [vmcnt]; BAR}
__global__ __launch_bounds__(512, 2) void snn_main(
    const unsigned short* __restrict__ xb, const float* __restrict__ xn,
    const int* __restrict__ y, const unsigned int* __restrict__ Tp,
    float* __restrict__ den, float* __restrict__ num) {
  // [buf][mat A=0/B=1][half][128 rows x 64 u16] ; rows are 128B, XOR-swizzled
  __shared__ __align__(16) unsigned short AB[2][2][2][128 * 64];

  const int t = threadIdx.x;
  const int lane = t & 63;
  const int w = t >> 6;        // 0..7
  const int wr = w >> 2;       // 0..1 (M)
  const int wc = w & 3;        // 0..3 (N)
  const int l15 = lane & 15;
  const int lg = lane >> 4;    // 0..3

  // ---- XCD-chunked swizzle (528 = 8*66, bijective) + triangle decode ----
  const int bid = blockIdx.x;
  const int ts = (bid & 7) * (NTILES / 8) + (bid >> 3);
  int I = (int)(32.5f - sqrtf(32.5f * 32.5f - 2.0f * (float)ts));
  while (I > 0 && (32 * I - (I * (I - 1)) / 2) > ts) --I;
  while ((32 * (I + 1) - ((I + 1) * I) / 2) <= ts) ++I;
  const int J = I + (ts - (32 * I - (I * (I - 1)) / 2));
  const int r0 = I * 256, c0 = J * 256;
  const bool diag = (I == J);

  const unsigned int tu = *Tp;
  const float tf = (tu & 0x7f800000u) ? __uint_as_float(tu) : (float)(int)tu;

  // staging: logical 16B chunk for this thread (involution with row&7)
  const int cl = (t & 7) ^ ((t >> 3) & 7);
  // frag-read byte offsets within a 128B row (kk = 0 / 1)
  const int offk0 = (lg * 16) ^ ((l15 & 7) << 4);
  const int offk1 = (64 + lg * 16) ^ ((l15 & 7) << 4);

  // issue one 16KB piece (2 x global_load_lds width-16 per thread)
  auto ISSUE = [&](int buf, int mat, int half, int s) {
    const int baseRow = (mat ? c0 : r0) + half * 128;
    const size_t colOff = (size_t)(s * 64 + cl * 8);
    unsigned short* dstbase = &AB[buf][mat][half][0];
#pragma unroll
    for (int i = 0; i < 2; ++i) {
      const int row128 = (t >> 3) + i * 64;
      const unsigned short* src = xb + (size_t)(baseRow + row128) * DK + colOff;
      __builtin_amdgcn_global_load_lds(
          (const __attribute__((address_space(1))) void*)src,
          (__attribute__((address_space(3))) void*)((char*)dstbase + (i * 512 + t) * 16),
          16, 0, 0);
    }
  };
  auto FRAG = [&](const unsigned short* base, int localRow, int off) -> bf16x8 {
    return *(const bf16x8*)((const char*)base + localRow * 128 + off);
  };

  // ---- prologue: tile0 fully + tile1 {A0,B0}; leave {0.A1,1.A0,1.B0} in flight
  ISSUE(0, 0, 0, 0);  // 0.A0
  ISSUE(0, 1, 0, 0);  // 0.B0
  ISSUE(0, 1, 1, 0);  // 0.B1
  ISSUE(0, 0, 1, 0);  // 0.A1
  ISSUE(1, 0, 0, 1);  // 1.A0
  ISSUE(1, 1, 0, 1);  // 1.B0
  asm volatile("s_waitcnt vmcnt(6)" ::: "memory");
  BAR();

  f32x4 acc[8][4];
#pragma unroll
  for (int m = 0; m < 8; ++m)
#pragma unroll
    for (int ni = 0; ni < 4; ++ni) acc[m][ni] = (f32x4){0.f, 0.f, 0.f, 0.f};

  for (int T = 0; T < NT; ++T) {
    const int buf = T & 1, nbuf = buf ^ 1;
    const unsigned short* A0 = &AB[buf][0][0][0];
    const unsigned short* A1 = &AB[buf][0][1][0];
    const unsigned short* B0 = &AB[buf][1][0][0];
    const unsigned short* B1 = &AB[buf][1][1][0];
    bf16x8 af[4], bv[4];

    // ---- P0: kk0, A-half0 ----
#pragma unroll
    for (int mi = 0; mi < 4; ++mi)
      af[mi] = FRAG(A0, (2 * mi + wr) * 16 + l15, offk0);
#pragma unroll
    for (int ni = 0; ni < 4; ++ni)
      bv[ni] = FRAG(ni < 2 ? B0 : B1, (((4 * ni + wc) * 16 + l15) & 127), offk0);
    if (T + 1 < NT) ISSUE(nbuf, 1, 1, T + 1);          // (T+1).B1
    BAR();
    __builtin_amdgcn_sched_barrier(0);
    __builtin_amdgcn_s_setprio(1);
#pragma unroll
    for (int mi = 0; mi < 4; ++mi)
#pragma unroll
      for (int ni = 0; ni < 4; ++ni)
        acc[mi][ni] = MFMA16(af[mi], bv[ni], acc[mi][ni]);
    __builtin_amdgcn_s_setprio(0);
    if (T + 1 < NT) { asm volatile("s_waitcnt vmcnt(6)" ::: "memory"); }
    else            { asm volatile("s_waitcnt vmcnt(0)" ::: "memory"); }
    BAR();

    // ---- P1: kk0, A-half1 (reuse bv) ----
#pragma unroll
    for (int mi = 0; mi < 4; ++mi)
      af[mi] = FRAG(A1, (2 * mi + wr) * 16 + l15, offk0);
    if (T + 1 < NT) ISSUE(nbuf, 0, 1, T + 1);          // (T+1).A1
    BAR();
    __builtin_amdgcn_sched_barrier(0);
    __builtin_amdgcn_s_setprio(1);
#pragma unroll
    for (int mi = 0; mi < 4; ++mi)
#pragma unroll
      for (int ni = 0; ni < 4; ++ni)
        acc[mi + 4][ni] = MFMA16(af[mi], bv[ni], acc[mi + 4][ni]);
    __builtin_amdgcn_s_setprio(0);
    BAR();

    // ---- P2: kk1, A-half0 ----
#pragma unroll
    for (int mi = 0; mi < 4; ++mi)
      af[mi] = FRAG(A0, (2 * mi + wr) * 16 + l15, offk1);
#pragma unroll
    for (int ni = 0; ni < 4; ++ni)
      bv[ni] = FRAG(ni < 2 ? B0 : B1, (((4 * ni + wc) * 16 + l15) & 127), offk1);
    BAR();
    __builtin_amdgcn_sched_barrier(0);
    __builtin_amdgcn_s_setprio(1);
#pragma unroll
    for (int mi = 0; mi < 4; ++mi)
#pragma unroll
      for (int ni = 0; ni < 4; ++ni)
        acc[mi][ni] = MFMA16(af[mi], bv[ni], acc[mi][ni]);
    __builtin_amdgcn_s_setprio(0);
    BAR();

    // ---- P3: kk1, A-half1 ----
#pragma unroll
    for (int mi = 0; mi < 4; ++mi)
      af[mi] = FRAG(A1, (2 * mi + wr) * 16 + l15, offk1);
    if (T + 2 < NT) { ISSUE(buf, 0, 0, T + 2); ISSUE(buf, 1, 0, T + 2); }  // (T+2).A0,B0
    BAR();
    __builtin_amdgcn_sched_barrier(0);
    __builtin_amdgcn_s_setprio(1);
#pragma unroll
    for (int mi = 0; mi < 4; ++mi)
#pragma unroll
      for (int ni = 0; ni < 4; ++ni)
        acc[mi + 4][ni] = MFMA16(af[mi], bv[ni], acc[mi + 4][ni]);
    __builtin_amdgcn_s_setprio(0);
    if (T + 2 < NT)       { asm volatile("s_waitcnt vmcnt(6)" ::: "memory"); }
    else if (T + 2 == NT) { asm volatile("s_waitcnt vmcnt(2)" ::: "memory"); }
    BAR();
  }

  // ---- load xn/y into (now dead) LDS buffer space ----
  float* xnA = (float*)&AB[0][0][0][0];
  float* xnB = xnA + 256;
  int* yA = (int*)(xnB + 256);
  int* yB = yA + 256;
  if (t < 256) { xnA[t] = xn[r0 + t]; yA[t] = y[r0 + t]; }
  else { const int u2 = t - 256; xnB[u2] = xn[c0 + u2]; yB[u2] = y[c0 + u2]; }
  BAR();

  // ---- epilogue: v = (same ? -1 : +1) * exp(-sqrt(max(d2,0))*T) ----
  float cxn[4]; int cy[4];
#pragma unroll
  for (int ni = 0; ni < 4; ++ni) {
    const int c_l = (4 * ni + wc) * 16 + l15;
    cxn[ni] = xnB[c_l]; cy[ni] = yB[c_l];
  }
#pragma unroll
  for (int m = 0; m < 8; ++m) {
    const int rowb = ((m & 3) * 2 + wr) * 16 + (m >> 2) * 128;
#pragma unroll
    for (int rg = 0; rg < 4; ++rg) {
      const int row_l = rowb + lg * 4 + rg;
      const int rG = r0 + row_l;
      const float rxn = xnA[row_l];
      const int ry = yA[row_l];
      float u = 0.f, av = 0.f;
#pragma unroll
      for (int ni = 0; ni < 4; ++ni) {
        const int cG = c0 + (4 * ni + wc) * 16 + l15;
        const float a = acc[m][ni][rg];
        const float d2 = fmaxf(rxn + cxn[ni] - 2.0f * a, 0.f);
        const float p = (rG == cG) ? 0.f : __expf(-sqrtf(d2) * tf);
        const float v = (ry == cy[ni]) ? -p : p;
        acc[m][ni][rg] = v;
        u += v; av += fabsf(v);
      }
#pragma unroll
      for (int mm = 8; mm >= 1; mm >>= 1) {
        u += __shfl_xor(u, mm); av += __shfl_xor(av, mm);
      }
      if (l15 == 0) {
        atomicAdd(&den[rG], av);
        atomicAdd(&num[rG], 0.5f * (av - u));
      }
    }
  }
  if (!diag) {  // column-side sums (transposed contribution)
#pragma unroll
    for (int ni = 0; ni < 4; ++ni) {
      float u = 0.f, av = 0.f;
#pragma unroll
      for (int m = 0; m < 8; ++m)
#pragma unroll
        for (int rg = 0; rg < 4; ++rg) {
          const float v = acc[m][ni][rg];
          u += v; av += fabsf(v);
        }
      u += __shfl_xor(u, 16); av += __shfl_xor(av, 16);
      u += __shfl_xor(u, 32); av += __shfl_xor(av, 32);
      if (lg == 0) {
        const int cG = c0 + (4 * ni + wc) * 16 + l15;
        atomicAdd(&den[cG], av);
        atomicAdd(&num[cG], 0.5f * (av - u));
      }
    }
  }
}

// ---------------- final: loss = mean(log den - log num) ----------------
__global__ __launch_bounds__(256) void snn_final(const float* __restrict__ den,
                                                 const float* __restrict__ num,
                                                 float* __restrict__ out) {
  __shared__ float red[256];
  const int t = threadIdx.x;
  float local = 0.f;
  for (int r = t; r < BN; r += 256) {
    const float sd = den[r], sn = num[r];
    const float d = logf(sd);
    const float n = (sn > 0.f) ? logf(sn) : 0.f;  // no positives -> num = 0 fixup
    local += d - n;
  }
  red[t] = local;
  __syncthreads();
  for (int s = 128; s >= 1; s >>= 1) {
    if (t < s) red[t] += red[t + s];
    __syncthreads();
  }
  if (t == 0) out[0] = red[0] * (1.0f / (float)BN);
}

extern "C" void kernel_launch(void* const* d_in, const int* in_sizes, int n_in,
                              void* d_out, int out_size, void* d_ws, size_t ws_size,
                              hipStream_t stream) {
  const float* x = (const float*)d_in[0];
  const int* y = (const int*)d_in[1];
  const unsigned int* Tp = (const unsigned int*)d_in[2];
  float* out = (float*)d_out;

  char* ws = (char*)d_ws;
  unsigned short* xb = (unsigned short*)ws;             // 16 MB bf16 x
  float* xn = (float*)(ws + (size_t)BN * DK * 2);       // 32 KB norms
  float* den = xn + BN;                                 // 32 KB
  float* num = den + BN;                                // 32 KB

  snn_prep<<<dim3(BN / 4), dim3(256), 0, stream>>>(x, xb, xn);
  hipMemsetAsync(den, 0, (size_t)2 * BN * sizeof(float), stream);
  snn_main<<<dim3(NTILES), dim3(512), 0, stream>>>(xb, xn, y, Tp, den, num);
  snn_final<<<dim3(1), dim3(256), 0, stream>>>(den, num, out);
}

// Round 5
// 132.142 us; speedup vs baseline: 1.4728x; 1.4728x over previous
//
#include <hip/hip_runtime.h>
#include <hip/hip_bf16.h>
#include <stdint.h>

#define BN 8192
#define DK 1024
#define NTILES 2080   // 64*65/2 upper-triangle 128x128 tiles

typedef __attribute__((ext_vector_type(4))) float f32x4;

// ---- fp32 -> OCP e4m3fn, RNE (handles normals, subnormals, clamp) ----
__device__ __forceinline__ unsigned int f2e4m3(float f) {
  const unsigned int u = __float_as_uint(f);
  const unsigned int sign = (u >> 24) & 0x80u;
  float a = fabsf(f);
  if (a >= 448.f) return sign | 0x7Eu;          // clamp to max finite
  if (a < 0.015625f) {                           // subnormal: ulp = 2^-9
    int m = (int)rintf(a * 512.f);               // 0..8 (8 == min normal)
    return sign | (unsigned int)m;
  }
  unsigned int x = __float_as_uint(a);
  x += 0x7FFFFu + ((x >> 20) & 1u);              // RNE to 3 mantissa bits
  const unsigned int e = (x >> 23) - 127u + 7u;  // e4m3 bias 7
  const unsigned int m = (x >> 20) & 7u;
  return sign | (e << 4) | m;
}

// ---------------- prep: e4m3 copy of x + fp32 row norms ----------------
// one wave per row, 4 waves per block; lane owns 16 consecutive floats
__global__ __launch_bounds__(256) void snn_prep(const float* __restrict__ x,
                                                unsigned char* __restrict__ xb,
                                                float* __restrict__ xn) {
  const int row = blockIdx.x * 4 + (threadIdx.x >> 6);
  const int lane = threadIdx.x & 63;
  const float4* src = (const float4*)(x + (size_t)row * DK) + lane * 4;
  float s = 0.f;
  unsigned int pk[4];
#pragma unroll
  for (int i = 0; i < 4; ++i) {
    float4 v = src[i];
    s = fmaf(v.x, v.x, s); s = fmaf(v.y, v.y, s);
    s = fmaf(v.z, v.z, s); s = fmaf(v.w, v.w, s);
    pk[i] = f2e4m3(v.x) | (f2e4m3(v.y) << 8) | (f2e4m3(v.z) << 16) |
            (f2e4m3(v.w) << 24);
  }
  uint4 o; o.x = pk[0]; o.y = pk[1]; o.z = pk[2]; o.w = pk[3];
  *(uint4*)(xb + (size_t)row * DK + lane * 16) = o;
#pragma unroll
  for (int m = 32; m >= 1; m >>= 1) s += __shfl_xor(s, m);
  if (lane == 0) xn[row] = s;
}

// ---------------- main: fp8 Gram on upper-triangle 128^2 tiles ----------------
// grid = 2080; block 256 (4 waves, 2x2 over the tile); BK=128 fp8 (128B rows)
__global__ __launch_bounds__(256, 4) void snn_main(
    const unsigned char* __restrict__ xb, const float* __restrict__ xn,
    const int* __restrict__ y, const unsigned int* __restrict__ Tp,
    float* __restrict__ den, float* __restrict__ num) {
  __shared__ __align__(16) unsigned char As[128 * 128];  // 16B-chunk XOR-swizzled
  __shared__ __align__(16) unsigned char Bs[128 * 128];
  __shared__ float xnA[128], xnB[128];
  __shared__ int yA[128], yB[128];

  const int t = threadIdx.x;
  const int lane = t & 63;
  const int w = t >> 6;
  const int wr = w >> 1, wc = w & 1;
  const int l15 = lane & 15;
  const int lg = lane >> 4;

  // ---- XCD-chunked swizzle (2080 = 8*260, bijective) + triangle decode ----
  const int bid = blockIdx.x;
  const int ts = (bid & 7) * (NTILES / 8) + (bid >> 3);
  int I = (int)(64.5f - sqrtf(64.5f * 64.5f - 2.0f * (float)ts));
  while (I > 0 && (64 * I - (I * (I - 1)) / 2) > ts) --I;
  while ((64 * (I + 1) - ((I + 1) * I) / 2) <= ts) ++I;
  const int J = I + (ts - (64 * I - (I * (I - 1)) / 2));
  const int r0 = I * 128, c0 = J * 128;
  const bool diag = (I == J);

  const unsigned int tu = *Tp;
  const float tf = (tu & 0x7f800000u) ? __uint_as_float(tu) : (float)(int)tu;

  if (t < 128) {
    xnA[t] = xn[r0 + t]; yA[t] = y[r0 + t];
    xnB[t] = xn[c0 + t]; yB[t] = y[c0 + t];
  }

  f32x4 acc[4][4];
#pragma unroll
  for (int mi = 0; mi < 4; ++mi)
#pragma unroll
    for (int ni = 0; ni < 4; ++ni) acc[mi][ni] = (f32x4){0.f, 0.f, 0.f, 0.f};

  for (int kt = 0; kt < DK; kt += 128) {
    // stage A(128x128B), B(128x128B); swizzle on the GLOBAL source so the
    // LDS dest stays linear (global_load_lds requirement). 8 chunks/row.
#pragma unroll
    for (int i = 0; i < 4; ++i) {
      int linear = i * 256 + t;       // 0..1023
      int row = linear >> 3;          // 0..127
      int cg = linear & 7;            // physical 16B chunk
      int cl = cg ^ (row & 7);        // logical chunk
      const unsigned char* sa = xb + (size_t)(r0 + row) * DK + kt + cl * 16;
      const unsigned char* sb = xb + (size_t)(c0 + row) * DK + kt + cl * 16;
      __builtin_amdgcn_global_load_lds(
          (const __attribute__((address_space(1))) void*)sa,
          (__attribute__((address_space(3))) void*)(As + linear * 16), 16, 0, 0);
      __builtin_amdgcn_global_load_lds(
          (const __attribute__((address_space(1))) void*)sb,
          (__attribute__((address_space(3))) void*)(Bs + linear * 16), 16, 0, 0);
    }
    __syncthreads();
#pragma unroll
    for (int kk = 0; kk < 4; ++kk) {
      long aL[4], bL[4];
#pragma unroll
      for (int mi = 0; mi < 4; ++mi) {
        const int row = wr * 64 + mi * 16 + l15;
        const int off = (((2 * kk + (lg >> 1)) ^ (row & 7)) << 4) + ((lg & 1) << 3);
        aL[mi] = *(const long*)(As + row * 128 + off);
      }
#pragma unroll
      for (int ni = 0; ni < 4; ++ni) {
        const int row = wc * 64 + ni * 16 + l15;
        const int off = (((2 * kk + (lg >> 1)) ^ (row & 7)) << 4) + ((lg & 1) << 3);
        bL[ni] = *(const long*)(Bs + row * 128 + off);
      }
#pragma unroll
      for (int mi = 0; mi < 4; ++mi)
#pragma unroll
        for (int ni = 0; ni < 4; ++ni)
          acc[mi][ni] = __builtin_amdgcn_mfma_f32_16x16x32_fp8_fp8(
              aL[mi], bL[ni], acc[mi][ni], 0, 0, 0);
    }
    __syncthreads();
  }

  // ---- epilogue: v = (same ? -1 : +1) * exp(-sqrt(max(d2,0))*T) ----
  // C layout: col = l15 + ni*16 + wc*64; row = lg*4+rg + mi*16 + wr*64
  float cxn[4]; int cy[4];
#pragma unroll
  for (int ni = 0; ni < 4; ++ni) {
    const int c_l = wc * 64 + ni * 16 + l15;
    cxn[ni] = xnB[c_l]; cy[ni] = yB[c_l];
  }
#pragma unroll
  for (int mi = 0; mi < 4; ++mi) {
#pragma unroll
    for (int rg = 0; rg < 4; ++rg) {
      const int row_l = wr * 64 + mi * 16 + lg * 4 + rg;
      const int rG = r0 + row_l;
      const float rxn = xnA[row_l];
      const int ry = yA[row_l];
      float u = 0.f, av = 0.f;
#pragma unroll
      for (int ni = 0; ni < 4; ++ni) {
        const int cG = c0 + wc * 64 + ni * 16 + l15;
        const float a = acc[mi][ni][rg];
        const float d2 = fmaxf(rxn + cxn[ni] - 2.0f * a, 0.f);
        const float p = (rG == cG) ? 0.f : __expf(-sqrtf(d2) * tf);
        const float v = (ry == cy[ni]) ? -p : p;
        acc[mi][ni][rg] = v;
        u += v; av += fabsf(v);
      }
#pragma unroll
      for (int mm = 8; mm >= 1; mm >>= 1) {
        u += __shfl_xor(u, mm); av += __shfl_xor(av, mm);
      }
      if (l15 == 0) {
        atomicAdd(&den[rG], av);
        atomicAdd(&num[rG], 0.5f * (av - u));
      }
    }
  }
  if (!diag) {  // column-side sums (transposed contribution)
#pragma unroll
    for (int ni = 0; ni < 4; ++ni) {
      float u = 0.f, av = 0.f;
#pragma unroll
      for (int mi = 0; mi < 4; ++mi)
#pragma unroll
        for (int rg = 0; rg < 4; ++rg) {
          const float v = acc[mi][ni][rg];
          u += v; av += fabsf(v);
        }
      u += __shfl_xor(u, 16); av += __shfl_xor(av, 16);
      u += __shfl_xor(u, 32); av += __shfl_xor(av, 32);
      if (lg == 0) {
        const int cG = c0 + wc * 64 + ni * 16 + l15;
        atomicAdd(&den[cG], av);
        atomicAdd(&num[cG], 0.5f * (av - u));
      }
    }
  }
}

// ---------------- final: loss = mean(log den - log num) ----------------
__global__ __launch_bounds__(256) void snn_final(const float* __restrict__ den,
                                                 const float* __restrict__ num,
                                                 float* __restrict__ out) {
  __shared__ float red[256];
  const int t = threadIdx.x;
  float local = 0.f;
  for (int r = t; r < BN; r += 256) {
    const float sd = den[r], sn = num[r];
    const float d = logf(sd);
    const float n = (sn > 0.f) ? logf(sn) : 0.f;  // no positives -> num = 0 fixup
    local += d - n;
  }
  red[t] = local;
  __syncthreads();
  for (int s = 128; s >= 1; s >>= 1) {
    if (t < s) red[t] += red[t + s];
    __syncthreads();
  }
  if (t == 0) out[0] = red[0] * (1.0f / (float)BN);
}

extern "C" void kernel_launch(void* const* d_in, const int* in_sizes, int n_in,
                              void* d_out, int out_size, void* d_ws, size_t ws_size,
                              hipStream_t stream) {
  const float* x = (const float*)d_in[0];
  const int* y = (const int*)d_in[1];
  const unsigned int* Tp = (const unsigned int*)d_in[2];
  float* out = (float*)d_out;

  char* ws = (char*)d_ws;
  unsigned char* xb = (unsigned char*)ws;               // 8 MB fp8 x
  float* xn = (float*)(ws + (size_t)BN * DK);           // 32 KB norms
  float* den = xn + BN;                                 // 32 KB
  float* num = den + BN;                                // 32 KB

  snn_prep<<<dim3(BN / 4), dim3(256), 0, stream>>>(x, xb, xn);
  hipMemsetAsync(den, 0, (size_t)2 * BN * sizeof(float), stream);
  snn_main<<<dim3(NTILES), dim3(256), 0, stream>>>(xb, xn, y, Tp, den, num);
  snn_final<<<dim3(1), dim3(256), 0, stream>>>(den, num, out);
}